// Round 5
// baseline (634.636 us; speedup 1.0000x reference)
//
#include <hip/hip_runtime.h>
#include <math.h>

#define NBINS 18
#define NB 2
#define NC 16
#define FP 30
#define FA 50
#define NS 20
#define NT 1024
#define TS 128              // t per staging chunk
#define NCH (NT / TS)       // 8
#define PGSZ 15             // p's per block
#define NTHR 384
#define BSTR 136            // shorts per B row (128 + 8 pad) = 272 B, 16B-aligned
#define BINROW 256          // bytes per bins row: 128 t * 2B, unpadded (reads are broadcast)
#define BIN_OFF (2 * 64 * BSTR * 2)       // 34816
#define SMEM_B (BIN_OFF + PGSZ * BINROW)  // 38656 -> 4 blocks/CU
#define ACCW 52

typedef __attribute__((ext_vector_type(8))) short bf16x8;
typedef __attribute__((ext_vector_type(4))) float f32x4;
typedef __attribute__((ext_vector_type(2))) unsigned short u16x2;

__device__ inline float u2f(unsigned int u) { return __builtin_bit_cast(float, u); }
__device__ inline unsigned int f2u(float f) { return __builtin_bit_cast(unsigned int, f); }

template <bool DIRECT>
__global__ __launch_bounds__(NTHR, 6) void mi_mfma(const float* __restrict__ pha,
                                                   const float* __restrict__ amp,
                                                   const float* __restrict__ cut,
                                                   float* __restrict__ outp) {
    __shared__ __align__(16) char smem[SMEM_B];
    short* Bh = (short*)smem;
    float* accs = (float*)smem;           // epilogue reuse

    // block decode: pairs (g, g+8) share bcs's amp slice on the same XCD
    const int g   = blockIdx.x;
    const int pg  = (g >> 3) & 1;
    const int bcs = (g >> 4) * 8 + (g & 7);
    const int s   = bcs % NS;
    const int bc  = bcs / NS;
    const int p0  = pg * PGSZ;

    const int tid  = threadIdx.x;
    const int lane = tid & 63;
    const int w    = tid >> 6;            // 0..5
    const int l16  = lane & 15;
    const int quad = lane >> 4;

    // interior cutoffs (uniform -> SGPRs)
    float cuts[NBINS];
    #pragma unroll
    for (int j = 1; j <= 17; ++j) cuts[j] = cut[j];

    // per-lane one-hot row params: rows w*48 + mt*16 + l16
    int pm[3]; unsigned kx2[3];
    #pragma unroll
    for (int mt = 0; mt < 3; ++mt) {
        const int row = w * 48 + mt * 16 + l16;
        const int valid = row < PGSZ * NBINS;
        const int p = valid ? (row / NBINS) : (PGSZ - 1);
        const int kb = valid ? (row - p * NBINS) : 31;   // 31 never matches (bins<=17)
        pm[mt] = p;
        kx2[mt] = (unsigned)kb * 0x00010001u;
    }

    // count column (a=50): hi=1.0 bf16, lo=0 — written once, never overwritten
    for (int t = tid; t < TS; t += NTHR) {
        Bh[FA * BSTR + t] = (short)0x3F80;
        Bh[64 * BSTR + FA * BSTR + t] = 0;
    }

    f32x4 acc[3][4];
    #pragma unroll
    for (int mt = 0; mt < 3; ++mt)
        #pragma unroll
        for (int nt = 0; nt < 4; ++nt) acc[mt][nt] = (f32x4){0.f, 0.f, 0.f, 0.f};

    const size_t phabase0 = ((size_t)(bc * FP + p0) * NS + s) * NT;
    const size_t ampbase0 = ((size_t)bc * FA * NS + s) * NT;

    for (int ch = 0; ch < NCH; ++ch) {
        __syncthreads();   // prev chunk's MFMA reads done (iter 0: count-col visible)
        const size_t phabase = phabase0 + (size_t)ch * TS;
        const size_t ampbase = ampbase0 + (size_t)ch * TS;

        // ---- stage bins as u16 pairs: 960 pairs; threads<192 do 3, rest 2 ----
        auto stage_pair = [&](int i) {
            const int p  = i >> 6;
            const int tp = i & 63;
            const float2 v2 = *(const float2*)(pha + phabase + (size_t)p * (NS * NT) + 2 * tp);
            int b0 = 0, b1 = 0;
            #pragma unroll
            for (int j = 1; j <= 17; ++j) {
                b0 += (cuts[j] < v2.x) ? 1 : 0;
                b1 += (cuts[j] < v2.y) ? 1 : 0;
            }
            *(unsigned*)(smem + BIN_OFF + p * BINROW + tp * 4) =
                (unsigned)b0 | ((unsigned)b1 << 16);
        };
        stage_pair(tid);
        stage_pair(tid + NTHR);
        if (tid < 192) stage_pair(tid + 2 * NTHR);

        // ---- stage amp hi/lo planes: 1600 float4; all do 4, threads<64 do 5 ----
        auto stage_amp = [&](int i) {
            const int a_ = i >> 5, tq = i & 31;
            const float4 v4 = *(const float4*)(amp + ampbase + (size_t)a_ * (NS * NT) + tq * 4);
            const unsigned r0 = f2u(v4.x) + 0x8000u;   // round-half-up hi (lo captures residual exactly)
            const unsigned r1 = f2u(v4.y) + 0x8000u;
            const unsigned r2 = f2u(v4.z) + 0x8000u;
            const unsigned r3 = f2u(v4.w) + 0x8000u;
            const float l0 = v4.x - u2f(r0 & 0xFFFF0000u);
            const float l1 = v4.y - u2f(r1 & 0xFFFF0000u);
            const float l2 = v4.z - u2f(r2 & 0xFFFF0000u);
            const float l3 = v4.w - u2f(r3 & 0xFFFF0000u);
            uint2 hv, lv;
            hv.x = __builtin_amdgcn_perm(r1, r0, 0x07060302u);           // {bf16(v1),bf16(v0)}
            hv.y = __builtin_amdgcn_perm(r3, r2, 0x07060302u);
            lv.x = __builtin_amdgcn_perm(f2u(l1) + 0x8000u, f2u(l0) + 0x8000u, 0x07060302u);
            lv.y = __builtin_amdgcn_perm(f2u(l3) + 0x8000u, f2u(l2) + 0x8000u, 0x07060302u);
            short* dst = Bh + a_ * BSTR + tq * 4;
            *(uint2*)dst = hv;
            *(uint2*)(dst + 64 * BSTR) = lv;
        };
        #pragma unroll
        for (int r = 0; r < 4; ++r) stage_amp(tid + r * NTHR);
        if (tid < 64) stage_amp(tid + 4 * NTHR);

        __syncthreads();
        // ---- MFMA phase: 4 K-steps of 32 ----
        #pragma unroll
        for (int ks = 0; ks < 4; ++ks) {
            // A one-hot frags: b128 bins read (broadcast) + 3 packed ops per dword
            bf16x8 af[3];
            #pragma unroll
            for (int mt = 0; mt < 3; ++mt) {
                const uint4 d = *(const uint4*)(smem + BIN_OFF + pm[mt] * BINROW + ks * 64 + quad * 16);
                uint4 a4;
                const unsigned* dp = (const unsigned*)&d;
                unsigned* ap = (unsigned*)&a4;
                #pragma unroll
                for (int q = 0; q < 4; ++q) {
                    u16x2 xv = __builtin_bit_cast(u16x2, dp[q] ^ kx2[mt]);
                    u16x2 one = {1, 1};
                    u16x2 yv = xv - one;                        // v_pk_sub_u16: match half -> 0xFFFF
                    ap[q] = __builtin_bit_cast(unsigned, yv) & 0x3F803F80u;  // -> bf16 1.0
                }
                af[mt] = __builtin_bit_cast(bf16x8, a4);
            }
            bf16x8 bh[4], bl[4];
            #pragma unroll
            for (int nt = 0; nt < 4; ++nt) {
                const short* bp = Bh + (nt * 16 + l16) * BSTR + ks * 32 + quad * 8;
                bh[nt] = *(const bf16x8*)bp;
                bl[nt] = *(const bf16x8*)(bp + 64 * BSTR);
            }
            #pragma unroll
            for (int mt = 0; mt < 3; ++mt)
                #pragma unroll
                for (int nt = 0; nt < 4; ++nt)
                    acc[mt][nt] = __builtin_amdgcn_mfma_f32_16x16x32_bf16(af[mt], bh[nt], acc[mt][nt], 0, 0, 0);
            #pragma unroll
            for (int mt = 0; mt < 3; ++mt)
                #pragma unroll
                for (int nt = 0; nt < 4; ++nt)
                    acc[mt][nt] = __builtin_amdgcn_mfma_f32_16x16x32_bf16(af[mt], bl[nt], acc[mt][nt], 0, 0, 0);
        }
    }
    __syncthreads();   // last MFMA reads done before smem reuse

    // ---- epilogue: 3 phases of 5 p's (90 rows) through reused LDS ----
    const float ln18 = 2.8903717578961645f;
    const float inv_ln18 = 0.34598234401512115f;
    #pragma unroll 1
    for (int ph = 0; ph < 3; ++ph) {
        const int rlo = ph * 90, rhi = rlo + 90;
        #pragma unroll
        for (int mt = 0; mt < 3; ++mt) {
            #pragma unroll
            for (int nt = 0; nt < 4; ++nt) {
                const int col = nt * 16 + l16;
                if (col <= FA) {
                    #pragma unroll
                    for (int r2 = 0; r2 < 4; ++r2) {
                        const int row = w * 48 + mt * 16 + quad * 4 + r2;
                        if (row >= rlo && row < rhi)
                            accs[(row - rlo) * ACCW + col] = acc[mt][nt][r2];
                    }
                }
            }
        }
        __syncthreads();
        if (tid < 5 * FA) {
            const int pidx = tid / FA;
            const int a = tid - pidx * FA;
            float means[NBINS];
            float tot = 0.f;
            #pragma unroll
            for (int k = 0; k < NBINS; ++k) {
                const float sum = accs[(pidx * NBINS + k) * ACCW + a];
                const float cnt = accs[(pidx * NBINS + k) * ACCW + FA];
                const float m = sum / (cnt + 1e-9f);
                means[k] = m;
                tot += m;
            }
            const float rden = 1.0f / (tot + 1e-9f);
            float ent = 0.f;
            #pragma unroll
            for (int k = 0; k < NBINS; ++k) {
                const float pr = means[k] * rden;
                ent += pr * logf(pr + 1e-9f);
            }
            const float mi = (ln18 + ent) * inv_ln18;
            const int p = ph * 5 + pidx;
            const int oi = (bc * FP + p0 + p) * FA + a;
            if (DIRECT) {
                atomicAdd(&outp[oi], mi * (1.0f / NS));
            } else {
                outp[(size_t)s * (NB * NC * FP * FA) + oi] = mi;   // s-major: reduce coalesced
            }
        }
        __syncthreads();
    }
}

__global__ void mi_reduce(const float* __restrict__ partial, float* __restrict__ out) {
    const int i = blockIdx.x * 256 + threadIdx.x;
    const int n = NB * NC * FP * FA;
    if (i < n) {
        float acc = 0.f;
        #pragma unroll
        for (int j = 0; j < NS; ++j) acc += partial[(size_t)j * n + i];
        out[i] = acc * (1.0f / NS);
    }
}

extern "C" void kernel_launch(void* const* d_in, const int* in_sizes, int n_in,
                              void* d_out, int out_size, void* d_ws, size_t ws_size,
                              hipStream_t stream) {
    const float* pha = (const float*)d_in[0];
    const float* amp = (const float*)d_in[1];
    const float* cut = (const float*)d_in[2];
    float* out = (float*)d_out;

    const int nout = NB * NC * FP * FA;                      // 48000
    const size_t need = (size_t)nout * NS * sizeof(float);   // 3.84 MB
    const dim3 grid(NB * NC * NS * 2);                       // 1280

    if (ws_size >= need) {
        float* partial = (float*)d_ws;
        mi_mfma<false><<<grid, NTHR, 0, stream>>>(pha, amp, cut, partial);
        mi_reduce<<<(nout + 255) / 256, 256, 0, stream>>>(partial, out);
    } else {
        hipMemsetAsync(d_out, 0, (size_t)nout * sizeof(float), stream);
        mi_mfma<true><<<grid, NTHR, 0, stream>>>(pha, amp, cut, out);
    }
}